// Round 3
// baseline (921.194 us; speedup 1.0000x reference)
//
#include <hip/hip_runtime.h>
#include <math.h>

// GatedPrototypeDistillationLoss, MI355X gfx950 — bf16x3 MFMA, round 3.
// Changes vs round 2:
//  * E pre-normalized + bf16 hi/lo split in ws (kprep_e2) -> kmain A-path is
//    pure global_load_lds (no in-loop conversion VALU, no mid-step vmcnt chain)
//  * dual accumulator banks: kt tile accumulates into bank E/O by parity while
//    the previous kt's 64 softmax-digest slots run 4-per-step under the MFMAs
//  * fallback to round-2 kernels if ws_size < 69 MB.

#define NB 32768
#define ND 512
#define NK 2048
#define TEMPR 0.07f
#define INV_T 14.285714285714286f
#define DX 1.4285714e-4f  // near-tie margin in x-domain (=1e-5 sim / T)

typedef unsigned short u16;
using bf16x8 = __attribute__((ext_vector_type(8))) short;
using f32x16 = __attribute__((ext_vector_type(16))) float;

__device__ inline u16 bf_hi(float x) {  // fp32 -> bf16 bits, RNE
  unsigned u = __float_as_uint(x);
  u = u + 0x7FFFu + ((u >> 16) & 1u);
  return (u16)(u >> 16);
}
__device__ inline float bf_tof(u16 h) {
  return __uint_as_float(((unsigned)h) << 16);
}
__device__ inline void gload_lds16(const void* g, void* l) {
  __builtin_amdgcn_global_load_lds((const __attribute__((address_space(1))) void*)g,
                                   (__attribute__((address_space(3))) void*)l, 16, 0, 0);
}
#define MF(a, b, c) __builtin_amdgcn_mfma_f32_32x32x16_bf16((a), (b), (c), 0, 0, 0)

// ---------------- kernel 1: P -> normalized bf16 hi/lo; zero flag counter ----
__global__ __launch_bounds__(256) void kprep_p(const float* __restrict__ P,
                                               u16* __restrict__ Phi,
                                               u16* __restrict__ Plo,
                                               int* __restrict__ cnt) {
  if (blockIdx.x == 0 && threadIdx.x == 0) *cnt = 0;
  const int lane = threadIdx.x & 63, w = threadIdx.x >> 6;
  const int row = blockIdx.x * 4 + w;  // grid 512 -> 2048 rows
  const float4* pr = (const float4*)(P + (size_t)row * ND);
  float4 a = pr[lane], b = pr[lane + 64];
  float ss = a.x * a.x + a.y * a.y + a.z * a.z + a.w * a.w
           + b.x * b.x + b.y * b.y + b.z * b.z + b.w * b.w;
#pragma unroll
  for (int off = 32; off > 0; off >>= 1) ss += __shfl_xor(ss, off);
  const float inv = 1.0f / fmaxf(sqrtf(ss), 1e-12f);
  ushort4 h4, l4;
#define PCNV(dst_h, dst_l, f) { float n_ = (f) * inv; u16 hb_ = bf_hi(n_); \
  dst_h = hb_; dst_l = bf_hi(n_ - bf_tof(hb_)); }
  PCNV(h4.x, l4.x, a.x) PCNV(h4.y, l4.y, a.y) PCNV(h4.z, l4.z, a.z) PCNV(h4.w, l4.w, a.w)
  *(ushort4*)(Phi + (size_t)row * ND + lane * 4) = h4;
  *(ushort4*)(Plo + (size_t)row * ND + lane * 4) = l4;
  PCNV(h4.x, l4.x, b.x) PCNV(h4.y, l4.y, b.y) PCNV(h4.z, l4.z, b.z) PCNV(h4.w, l4.w, b.w)
  *(ushort4*)(Phi + (size_t)row * ND + (lane + 64) * 4) = h4;
  *(ushort4*)(Plo + (size_t)row * ND + (lane + 64) * 4) = l4;
}

// ---------------- kernel 2 (fast): E -> normalized bf16 hi/lo ----------------
__global__ __launch_bounds__(256) void kprep_e2(const float* __restrict__ E,
                                                u16* __restrict__ Ehi,
                                                u16* __restrict__ Elo) {
  const int lane = threadIdx.x & 63, w = threadIdx.x >> 6;
  const int row = blockIdx.x * 4 + w;  // grid 8192 -> 32768 rows
  const float4* er = (const float4*)(E + (size_t)row * ND);
  float4 a = er[lane], b = er[lane + 64];
  float ss = a.x * a.x + a.y * a.y + a.z * a.z + a.w * a.w
           + b.x * b.x + b.y * b.y + b.z * b.z + b.w * b.w;
#pragma unroll
  for (int off = 32; off > 0; off >>= 1) ss += __shfl_xor(ss, off);
  const float inv = 1.0f / fmaxf(sqrtf(ss), 1e-12f);
  ushort4 h4, l4;
  PCNV(h4.x, l4.x, a.x) PCNV(h4.y, l4.y, a.y) PCNV(h4.z, l4.z, a.z) PCNV(h4.w, l4.w, a.w)
  *(ushort4*)(Ehi + (size_t)row * ND + lane * 4) = h4;
  *(ushort4*)(Elo + (size_t)row * ND + lane * 4) = l4;
  PCNV(h4.x, l4.x, b.x) PCNV(h4.y, l4.y, b.y) PCNV(h4.z, l4.z, b.z) PCNV(h4.w, l4.w, b.w)
  *(ushort4*)(Ehi + (size_t)row * ND + (lane + 64) * 4) = h4;
  *(ushort4*)(Elo + (size_t)row * ND + (lane + 64) * 4) = l4;
}

// ---------------- kernel 2 (fallback): embedding inverse norms ----------------
__global__ __launch_bounds__(256) void kprep_e(const float* __restrict__ E,
                                               float* __restrict__ inv_e) {
  const int lane = threadIdx.x & 63, w = threadIdx.x >> 6;
  const int row = blockIdx.x * 4 + w;
  const float4* er = (const float4*)(E + (size_t)row * ND);
  float4 a = er[lane], b = er[lane + 64];
  float ss = a.x * a.x + a.y * a.y + a.z * a.z + a.w * a.w
           + b.x * b.x + b.y * b.y + b.z * b.z + b.w * b.w;
#pragma unroll
  for (int off = 32; off > 0; off >>= 1) ss += __shfl_xor(ss, off);
  if (lane == 0) inv_e[row] = 1.0f / fmaxf(sqrtf(ss), 1e-12f);
}
#undef PCNV

// online update: x-domain logit, fixed offset; near-tie flag per slot bit
#define UPDV(r, vv, pp) { \
  float x_ = fmaf((vv), INV_T, -INV_T); \
  float e_ = __expf(x_); \
  sS[r] += e_; uS[r] = fmaf(x_, e_, uS[r]); \
  float d_ = x_ - mx[r]; \
  bool up_ = d_ > 0.0f; \
  bool nr_ = fabsf(d_) < DX; \
  mx[r] = up_ ? x_ : mx[r]; \
  ix[r] = up_ ? (pp) : ix[r]; \
  unsigned b_ = 1u << (r); \
  fl = (up_ ? (fl & ~b_) : fl) | (nr_ ? b_ : 0u); }

// ================= kernel 3 (fast): MFMA GEMM + interleaved digest ===========
__global__ __launch_bounds__(256, 2) void kmain_v3(
    const float* __restrict__ BS,
    const u16* __restrict__ PhiG, const u16* __restrict__ PloG,
    const u16* __restrict__ EhiG, const u16* __restrict__ EloG,
    const float* __restrict__ CONF,
    float* __restrict__ tau_ws, float* __restrict__ gd, float* __restrict__ gate_out,
    int* __restrict__ cnt, int* __restrict__ flags) {
  __shared__ u16 Ahi[2][2048], Alo[2][2048];   // 64 rows x 32 d, dbuf
  __shared__ u16 Bhi[2][8192], Blo[2][8192];   // 256 protos x 32 d, dbuf

  const int t = threadIdx.x;
  const int lane = t & 63;
  const int w = t >> 6, wr = w >> 1, wc = w & 1;
  const int c = lane & 31, h = lane >> 5;
  const int swz = (blockIdx.x & 7) * 64 + (blockIdx.x >> 3);  // XCD swizzle (512=8*64)
  const int row0 = swz * 64;

  // A staging: thread t -> LDS slot t (linear dest), pre-swizzled global source
  const int arow_s = t >> 2, agp = t & 3;
  const int agsrc = agp ^ ((arow_s >> 1) & 3);
  const u16* EhiR = EhiG + (size_t)(row0 + arow_s) * ND + agsrc * 8;
  const u16* EloR = EloG + (size_t)(row0 + arow_s) * ND + agsrc * 8;

  // B staging per-instruction source offsets (pre-swizzled)
  int boff[4];
#pragma unroll
  for (int i = 0; i < 4; ++i) {
    int slot = w * 256 + i * 64 + lane;
    int rb = slot >> 2, gpb = slot & 3;
    int gsb = gpb ^ ((rb >> 1) & 3);
    boff[i] = rb * ND + gsb * 8;
  }

  // fragment-read constants
  const int arow4 = (wr * 32 + c) * 4;
  const int axor = ((wr * 32 + c) >> 1) & 3;
  const int bxor = (c >> 1) & 3;
  const int brow4 = (wc * 128 + c) * 4;

  f32x16 accE0, accE1, accE2, accE3, accO0, accO1, accO2, accO3;
#pragma unroll
  for (int i = 0; i < 16; ++i) {
    accE0[i] = 0.f; accE1[i] = 0.f; accE2[i] = 0.f; accE3[i] = 0.f;
    accO0[i] = 0.f; accO1[i] = 0.f; accO2[i] = 0.f; accO3[i] = 0.f;
  }
  float sS[16], uS[16], mx[16];
  int ix[16];
  unsigned fl = 0;
#pragma unroll
  for (int r = 0; r < 16; ++r) { sS[r] = 0.f; uS[r] = 0.f; mx[r] = -3.0e38f; ix[r] = 0; }

#define SB3(off, nx) { \
  _Pragma("unroll") \
  for (int i = 0; i < 4; ++i) { \
    gload_lds16(PhiG + (off) + boff[i], &Bhi[nx][(w * 256 + i * 64) * 8]); \
    gload_lds16(PloG + (off) + boff[i], &Blo[nx][(w * 256 + i * 64) * 8]); \
  } }
#define SA3(col, nx) { \
  gload_lds16(EhiR + (col), &Ahi[nx][t * 8]); \
  gload_lds16(EloR + (col), &Alo[nx][t * 8]); }

#define KS3(A0, A1, A2, A3, CUR, ks) { \
  const int ag_ = 2 * (ks) + h; \
  const int ao_ = (arow4 + (ag_ ^ axor)) * 8; \
  const bf16x8 ehi = *(const bf16x8*)&Ahi[CUR][ao_]; \
  const bf16x8 elo = *(const bf16x8*)&Alo[CUR][ao_]; \
  const int bo_ = (brow4 + (ag_ ^ bxor)) * 8; \
  const bf16x8 bh0 = *(const bf16x8*)&Bhi[CUR][bo_]; \
  const bf16x8 bh1 = *(const bf16x8*)&Bhi[CUR][bo_ + 1024]; \
  const bf16x8 bh2 = *(const bf16x8*)&Bhi[CUR][bo_ + 2048]; \
  const bf16x8 bh3 = *(const bf16x8*)&Bhi[CUR][bo_ + 3072]; \
  const bf16x8 bl0 = *(const bf16x8*)&Blo[CUR][bo_]; \
  const bf16x8 bl1 = *(const bf16x8*)&Blo[CUR][bo_ + 1024]; \
  const bf16x8 bl2 = *(const bf16x8*)&Blo[CUR][bo_ + 2048]; \
  const bf16x8 bl3 = *(const bf16x8*)&Blo[CUR][bo_ + 3072]; \
  A0 = MF(ehi, bh0, A0); A1 = MF(ehi, bh1, A1); \
  A2 = MF(ehi, bh2, A2); A3 = MF(ehi, bh3, A3); \
  A0 = MF(ehi, bl0, A0); A1 = MF(ehi, bl1, A1); \
  A2 = MF(ehi, bl2, A2); A3 = MF(ehi, bl3, A3); \
  A0 = MF(elo, bh0, A0); A1 = MF(elo, bh1, A1); \
  A2 = MF(elo, bh2, A2); A3 = MF(elo, bh3, A3); }

// One 16-step phase: MFMA kt tile (ktv) into bank A0..A3; digest bank D0..D3
// (kt = ktv-1) 4 slots/step when DG. cur buffer parity == s&1 (steps globally
// phase-aligned: each phase is 16 steps, phases start at even global step).
#define PH3(A0, A1, A2, A3, D0, D1, D2, D3, DG, ktv) { \
  const int kbB = (ktv) * (256 * ND); \
  const int pidD = ((ktv) - 1) * 256 + wc * 128 + c; \
  _Pragma("unroll") \
  for (int s = 0; s < 16; ++s) { \
    const int cur = s & 1, nxt = cur ^ 1; \
    const int sb = (s < 15) ? (kbB + (s + 1) * 32) : (kbB + 256 * ND); \
    const int sa = ((s < 15) ? (s + 1) : 0) * 32; \
    SB3(sb, nxt); \
    SA3(sa, nxt); \
    KS3(A0, A1, A2, A3, cur, 0); \
    KS3(A0, A1, A2, A3, cur, 1); \
    if (DG) { \
      UPDV(s, D0[s], pidD) \
      UPDV(s, D1[s], pidD + 32) \
      UPDV(s, D2[s], pidD + 64) \
      UPDV(s, D3[s], pidD + 96) \
      D0[s] = 0.f; D1[s] = 0.f; D2[s] = 0.f; D3[s] = 0.f; \
    } \
    __syncthreads(); \
  } }

  // prologue: stage tile (kt=0, dt=0) into buffer 0
  SB3(0, 0);
  SA3(0, 0);
  __syncthreads();

  for (int kk = 0; kk < 4; ++kk) {
    PH3(accE0, accE1, accE2, accE3, accO0, accO1, accO2, accO3, (kk > 0), kk * 2)
    PH3(accO0, accO1, accO2, accO3, accE0, accE1, accE2, accE3, 1, kk * 2 + 1)
  }
  // tail digest: kt = 7 (bank O)
  {
    const int pidF = 7 * 256 + wc * 128 + c;
#pragma unroll
    for (int s = 0; s < 16; ++s) {
      UPDV(s, accO0[s], pidF)
      UPDV(s, accO1[s], pidF + 32)
      UPDV(s, accO2[s], pidF + 64)
      UPDV(s, accO3[s], pidF + 96)
    }
  }

  // ---- butterfly merge across the 32 proto-partition lanes ----
#pragma unroll
  for (int off = 1; off < 32; off <<= 1) {
    unsigned flo = __shfl_xor(fl, off);
    unsigned nfl = 0u;
#pragma unroll
    for (int r = 0; r < 16; ++r) {
      float mo = __shfl_xor(mx[r], off);
      float so = __shfl_xor(sS[r], off);
      float uo = __shfl_xor(uS[r], off);
      int io = __shfl_xor(ix[r], off);
      sS[r] += so; uS[r] += uo;
      float d = mo - mx[r];
      bool up = d > 0.0f;
      bool nr = fabsf(d) < DX;
      bool f0 = (fl >> r) & 1u, f1 = (flo >> r) & 1u;
      bool fw = (up ? f1 : f0) || nr;
      mx[r] = up ? mo : mx[r];
      ix[r] = up ? io : ix[r];
      nfl |= fw ? (1u << r) : 0u;
    }
    fl = nfl;
  }

  // ---- cross-wave (wc) merge via LDS (alias onto Ahi, compute done) ----
  float* mg = (float*)&Ahi[0][0];  // [wr][wc][32 rows][6] = 768 floats
  if (c == 0) {
#pragma unroll
    for (int r = 0; r < 16; ++r) {
      int rowl = (r & 3) + 8 * (r >> 2) + 4 * h;
      int base = ((wr * 2 + wc) * 32 + rowl) * 6;
      mg[base + 0] = mx[r];
      mg[base + 1] = sS[r];
      mg[base + 2] = uS[r];
      mg[base + 3] = __int_as_float(ix[r]);
      mg[base + 4] = ((fl >> r) & 1u) ? 1.0f : 0.0f;
    }
  }
  __syncthreads();

  if ((w & 1) == 0 && lane < 32) {
    const int rowl = lane;
    const int b0 = ((wr * 2 + 0) * 32 + rowl) * 6;
    const int b1 = ((wr * 2 + 1) * 32 + rowl) * 6;
    float m0 = mg[b0], s0 = mg[b0 + 1], u0 = mg[b0 + 2];
    int i0 = __float_as_int(mg[b0 + 3]);
    bool f0 = mg[b0 + 4] != 0.0f;
    float m1 = mg[b1], s1 = mg[b1 + 1], u1 = mg[b1 + 2];
    int i1 = __float_as_int(mg[b1 + 3]);
    bool f1 = mg[b1 + 4] != 0.0f;
    float d = m1 - m0;
    bool up = d > 0.0f;
    float m = up ? m1 : m0;
    int idx = up ? i1 : i0;
    bool flg = (up ? f1 : f0) || (fabsf(d) < DX);
    float s = s0 + s1, u = u0 + u1;

    float ent = logf(s) - u / s;  // = lse - E[logit]
    float tau = 0.5f - 0.2f * (ent * (1.0f / (7.6246190071f + 1e-8f)));
    float simmax = fmaf(m, TEMPR, 1.0f);  // m is (sim-1)/T
    float dist = sqrtf(fmaxf(2.0f - 2.0f * simmax, 0.0f));
    int grow = row0 + wr * 32 + rowl;
    float g = CONF[idx] / (1.0f + __expf(-(BS[grow] - tau) * INV_T));
    gate_out[grow] = g;
    gd[grow] = g * dist;
    tau_ws[grow] = tau;
    if (flg) {
      int p = atomicAdd(cnt, 1);
      flags[p] = grow;
    }
  }
}

// ================= kernel 3 (fallback): round-2 kmain =======================
__global__ __launch_bounds__(256, 2) void kmain_fb(
    const float* __restrict__ E, const float* __restrict__ BS,
    const u16* __restrict__ Phi, const u16* __restrict__ Plo,
    const float* __restrict__ CONF, const float* __restrict__ inv_e,
    float* __restrict__ tau_ws, float* __restrict__ gd, float* __restrict__ gate_out,
    int* __restrict__ cnt, int* __restrict__ flags) {
  __shared__ u16 Ahi[2][2048], Alo[2][2048];
  __shared__ u16 Bhi[2][8192], Blo[2][8192];

  const int t = threadIdx.x;
  const int lane = t & 63;
  const int w = t >> 6, wr = w >> 1, wc = w & 1;
  const int c = lane & 31, h = lane >> 5;
  const int swz = (blockIdx.x & 7) * 64 + (blockIdx.x >> 3);
  const int row0 = swz * 64;

  const int arow_s = t >> 2, agp = t & 3;
  const int agsrc = agp ^ ((arow_s >> 1) & 3);
  const float inve = inv_e[row0 + arow_s];
  const float* Asrc = E + (size_t)(row0 + arow_s) * ND + agsrc * 8;

  int boff[4];
#pragma unroll
  for (int i = 0; i < 4; ++i) {
    int slot = w * 256 + i * 64 + lane;
    int rb = slot >> 2, gpb = slot & 3;
    int gsb = gpb ^ ((rb >> 1) & 3);
    boff[i] = rb * ND + gsb * 8;
  }

  const int arow4 = (wr * 32 + c) * 4;
  const int axor = ((wr * 32 + c) >> 1) & 3;
  const int bxor = (c >> 1) & 3;
  const int brow4 = (wc * 128 + c) * 4;

  f32x16 acc0, acc1, acc2, acc3;
#pragma unroll
  for (int i = 0; i < 16; ++i) { acc0[i] = 0.f; acc1[i] = 0.f; acc2[i] = 0.f; acc3[i] = 0.f; }
  float sS[16], uS[16], mx[16];
  int ix[16];
  unsigned fl = 0;
#pragma unroll
  for (int r = 0; r < 16; ++r) { sS[r] = 0.f; uS[r] = 0.f; mx[r] = -3.0e38f; ix[r] = 0; }

#define STAGE_B(tkt, tdt, nx) { \
  const int ko_ = (tkt) * 256 * ND + (tdt) * 32; \
  _Pragma("unroll") \
  for (int i = 0; i < 4; ++i) { \
    gload_lds16(Phi + ko_ + boff[i], &Bhi[nx][(w * 256 + i * 64) * 8]); \
    gload_lds16(Plo + ko_ + boff[i], &Blo[nx][(w * 256 + i * 64) * 8]); \
  } }
#define LOAD_A(tdt) { const float4* ap_ = (const float4*)(Asrc + (tdt) * 32); \
  a0 = ap_[0]; a1 = ap_[1]; }
#define ACNV(j, f) { float n_ = (f) * inve; u16 hb_ = bf_hi(n_); \
  hv[j] = (short)hb_; lv[j] = (short)bf_hi(n_ - bf_tof(hb_)); }
#define WRITE_A(nx) { bf16x8 hv, lv; \
  ACNV(0, a0.x) ACNV(1, a0.y) ACNV(2, a0.z) ACNV(3, a0.w) \
  ACNV(4, a1.x) ACNV(5, a1.y) ACNV(6, a1.z) ACNV(7, a1.w) \
  *(bf16x8*)&Ahi[nx][t * 8] = hv; *(bf16x8*)&Alo[nx][t * 8] = lv; }
#define KSTEP(ks) { \
  const int ag_ = 2 * (ks) + h; \
  const int ao_ = (arow4 + (ag_ ^ axor)) * 8; \
  const bf16x8 ehi = *(const bf16x8*)&Ahi[cur][ao_]; \
  const bf16x8 elo = *(const bf16x8*)&Alo[cur][ao_]; \
  const int bo_ = (brow4 + (ag_ ^ bxor)) * 8; \
  const bf16x8 bh0 = *(const bf16x8*)&Bhi[cur][bo_]; \
  const bf16x8 bh1 = *(const bf16x8*)&Bhi[cur][bo_ + 1024]; \
  const bf16x8 bh2 = *(const bf16x8*)&Bhi[cur][bo_ + 2048]; \
  const bf16x8 bh3 = *(const bf16x8*)&Bhi[cur][bo_ + 3072]; \
  const bf16x8 bl0 = *(const bf16x8*)&Blo[cur][bo_]; \
  const bf16x8 bl1 = *(const bf16x8*)&Blo[cur][bo_ + 1024]; \
  const bf16x8 bl2 = *(const bf16x8*)&Blo[cur][bo_ + 2048]; \
  const bf16x8 bl3 = *(const bf16x8*)&Blo[cur][bo_ + 3072]; \
  acc0 = MF(ehi, bh0, acc0); acc1 = MF(ehi, bh1, acc1); \
  acc2 = MF(ehi, bh2, acc2); acc3 = MF(ehi, bh3, acc3); \
  acc0 = MF(ehi, bl0, acc0); acc1 = MF(ehi, bl1, acc1); \
  acc2 = MF(ehi, bl2, acc2); acc3 = MF(ehi, bl3, acc3); \
  acc0 = MF(elo, bh0, acc0); acc1 = MF(elo, bh1, acc1); \
  acc2 = MF(elo, bh2, acc2); acc3 = MF(elo, bh3, acc3); }

  float4 a0, a1;
  STAGE_B(0, 0, 0);
  LOAD_A(0);
  WRITE_A(0);
  __syncthreads();

  for (int step = 0; step < 128; ++step) {
    const int cur = step & 1, nxt = cur ^ 1;
    const int ns = (step < 127) ? step + 1 : 127;
    STAGE_B(ns >> 4, ns & 15, nxt);
    LOAD_A(ns & 15);
    KSTEP(0);
    KSTEP(1);
    WRITE_A(nxt);
    if ((step & 15) == 15) {
      const int pidb = (step >> 4) * 256 + wc * 128 + c;
#pragma unroll
      for (int r = 0; r < 16; ++r) {
        UPDV(r, acc0[r], pidb)
        UPDV(r, acc1[r], pidb + 32)
        UPDV(r, acc2[r], pidb + 64)
        UPDV(r, acc3[r], pidb + 96)
        acc0[r] = 0.f; acc1[r] = 0.f; acc2[r] = 0.f; acc3[r] = 0.f;
      }
    }
    __syncthreads();
  }

#pragma unroll
  for (int off = 1; off < 32; off <<= 1) {
    unsigned flo = __shfl_xor(fl, off);
    unsigned nfl = 0u;
#pragma unroll
    for (int r = 0; r < 16; ++r) {
      float mo = __shfl_xor(mx[r], off);
      float so = __shfl_xor(sS[r], off);
      float uo = __shfl_xor(uS[r], off);
      int io = __shfl_xor(ix[r], off);
      sS[r] += so; uS[r] += uo;
      float d = mo - mx[r];
      bool up = d > 0.0f;
      bool nr = fabsf(d) < DX;
      bool f0 = (fl >> r) & 1u, f1 = (flo >> r) & 1u;
      bool fw = (up ? f1 : f0) || nr;
      mx[r] = up ? mo : mx[r];
      ix[r] = up ? io : ix[r];
      nfl |= fw ? (1u << r) : 0u;
    }
    fl = nfl;
  }

  float* mg = (float*)&Ahi[0][0];
  if (c == 0) {
#pragma unroll
    for (int r = 0; r < 16; ++r) {
      int rowl = (r & 3) + 8 * (r >> 2) + 4 * h;
      int base = ((wr * 2 + wc) * 32 + rowl) * 6;
      mg[base + 0] = mx[r];
      mg[base + 1] = sS[r];
      mg[base + 2] = uS[r];
      mg[base + 3] = __int_as_float(ix[r]);
      mg[base + 4] = ((fl >> r) & 1u) ? 1.0f : 0.0f;
    }
  }
  __syncthreads();

  if ((w & 1) == 0 && lane < 32) {
    const int rowl = lane;
    const int b0 = ((wr * 2 + 0) * 32 + rowl) * 6;
    const int b1 = ((wr * 2 + 1) * 32 + rowl) * 6;
    float m0 = mg[b0], s0 = mg[b0 + 1], u0 = mg[b0 + 2];
    int i0 = __float_as_int(mg[b0 + 3]);
    bool f0 = mg[b0 + 4] != 0.0f;
    float m1 = mg[b1], s1 = mg[b1 + 1], u1 = mg[b1 + 2];
    int i1 = __float_as_int(mg[b1 + 3]);
    bool f1 = mg[b1 + 4] != 0.0f;
    float d = m1 - m0;
    bool up = d > 0.0f;
    float m = up ? m1 : m0;
    int idx = up ? i1 : i0;
    bool flg = (up ? f1 : f0) || (fabsf(d) < DX);
    float s = s0 + s1, u = u0 + u1;
    float ent = logf(s) - u / s;
    float tau = 0.5f - 0.2f * (ent * (1.0f / (7.6246190071f + 1e-8f)));
    float simmax = fmaf(m, TEMPR, 1.0f);
    float dist = sqrtf(fmaxf(2.0f - 2.0f * simmax, 0.0f));
    int grow = row0 + wr * 32 + rowl;
    float g = CONF[idx] / (1.0f + __expf(-(BS[grow] - tau) * INV_T));
    gate_out[grow] = g;
    gd[grow] = g * dist;
    tau_ws[grow] = tau;
    if (flg) {
      int p = atomicAdd(cnt, 1);
      flags[p] = grow;
    }
  }
}

// ---------------- kernel 4: fp32 rescore of near-tie rows ----------------
__global__ __launch_bounds__(256) void krescore(
    const float* __restrict__ E, const float* __restrict__ P,
    const float* __restrict__ BS, const float* __restrict__ CONF,
    const float* __restrict__ tau_ws, const int* __restrict__ cnt,
    const int* __restrict__ flags, float* __restrict__ gd,
    float* __restrict__ gate_out) {
  __shared__ float en[512];
  __shared__ float red[256];
  __shared__ int redi[256];
  __shared__ float sinv;
  const int n = *cnt;
  const int t = threadIdx.x;
  for (int j = blockIdx.x; j < n; j += gridDim.x) {
    const int row = flags[j];
    float2 v = ((const float2*)(E + (size_t)row * ND))[t];
    red[t] = v.x * v.x + v.y * v.y;
    __syncthreads();
    for (int o = 128; o > 0; o >>= 1) {
      if (t < o) red[t] += red[t + o];
      __syncthreads();
    }
    if (t == 0) sinv = 1.0f / fmaxf(sqrtf(red[0]), 1e-12f);
    __syncthreads();
    en[2 * t] = v.x * sinv;
    en[2 * t + 1] = v.y * sinv;
    __syncthreads();
    float best = -3.0e38f;
    int bidx = 0;
    for (int k = 0; k < 8; ++k) {
      const int p = k * 256 + t;
      const float4* pr = (const float4*)(P + (size_t)p * ND);
      float dot = 0.f, pp = 0.f;
      for (int i = 0; i < 128; ++i) {
        float4 a = pr[i];
        float4 e4 = ((const float4*)en)[i];
        dot = fmaf(a.x, e4.x, dot); dot = fmaf(a.y, e4.y, dot);
        dot = fmaf(a.z, e4.z, dot); dot = fmaf(a.w, e4.w, dot);
        pp = fmaf(a.x, a.x, pp); pp = fmaf(a.y, a.y, pp);
        pp = fmaf(a.z, a.z, pp); pp = fmaf(a.w, a.w, pp);
      }
      float sim = dot / fmaxf(sqrtf(pp), 1e-12f);
      if (sim > best) { best = sim; bidx = p; }
    }
    red[t] = best;
    redi[t] = bidx;
    __syncthreads();
    if (t == 0) {
      float bb = red[0];
      int bi = redi[0];
      for (int i = 1; i < 256; ++i) {
        float vv = red[i];
        int ii = redi[i];
        if (vv > bb || (vv == bb && ii < bi)) { bb = vv; bi = ii; }
      }
      float tau = tau_ws[row];
      float dist = sqrtf(fmaxf(2.0f - 2.0f * bb, 0.0f));
      float g = CONF[bi] / (1.0f + __expf(-(BS[row] - tau) * INV_T));
      gate_out[row] = g;
      gd[row] = g * dist;
    }
    __syncthreads();
  }
}

// ---------------- kernel 5: deterministic mean ----------------
__global__ __launch_bounds__(1024) void kreduce(const float* __restrict__ gd,
                                                float* __restrict__ out0) {
  __shared__ float red[1024];
  const int t = threadIdx.x;
  float s = 0.f;
  const float4* g4 = (const float4*)gd;
  for (int i = t; i < 8192; i += 1024) {
    float4 v = g4[i];
    s += (v.x + v.y) + (v.z + v.w);
  }
  red[t] = s;
  __syncthreads();
  for (int off = 512; off > 0; off >>= 1) {
    if (t < off) red[t] += red[t + off];
    __syncthreads();
  }
  if (t == 0) out0[0] = red[0] * (1.0f / 32768.0f);
}

extern "C" void kernel_launch(void* const* d_in, const int* in_sizes, int n_in,
                              void* d_out, int out_size, void* d_ws, size_t ws_size,
                              hipStream_t stream) {
  const float* E = (const float*)d_in[0];
  const float* BS = (const float*)d_in[1];
  const float* P = (const float*)d_in[2];
  const float* CONF = (const float*)d_in[3];
  float* out = (float*)d_out;  // [0]=L_proto, [1..32768]=gate

  char* wsb = (char*)d_ws;
  const bool fast = ws_size >= (size_t)69 * 1024 * 1024;

  if (fast) {
    u16* Phi = (u16*)wsb;                                   // 2 MB @ 0
    u16* Plo = (u16*)(wsb + ((size_t)2 << 20));             // 2 MB @ 2M
    u16* Ehi = (u16*)(wsb + ((size_t)4 << 20));             // 32 MB @ 4M
    u16* Elo = (u16*)(wsb + ((size_t)36 << 20));            // 32 MB @ 36M
    float* tau_ws = (float*)(wsb + ((size_t)68 << 20));     // 128 KB
    float* gd = (float*)(wsb + ((size_t)68 << 20) + 131072);
    int* flags = (int*)(wsb + ((size_t)68 << 20) + 2 * 131072);
    int* cnt = (int*)(wsb + ((size_t)68 << 20) + 3 * 131072);

    kprep_p<<<512, 256, 0, stream>>>(P, Phi, Plo, cnt);
    kprep_e2<<<8192, 256, 0, stream>>>(E, Ehi, Elo);
    kmain_v3<<<512, 256, 0, stream>>>(BS, Phi, Plo, Ehi, Elo, CONF, tau_ws, gd,
                                      out + 1, cnt, flags);
    krescore<<<64, 256, 0, stream>>>(E, P, BS, CONF, tau_ws, cnt, flags, gd, out + 1);
    kreduce<<<1, 1024, 0, stream>>>(gd, out);
  } else {
    u16* Phi = (u16*)wsb;
    u16* Plo = (u16*)(wsb + ((size_t)2 << 20));
    float* inv_e = (float*)(wsb + ((size_t)4 << 20));
    float* tau_ws = (float*)(wsb + ((size_t)4 << 20) + 131072);
    float* gd = (float*)(wsb + ((size_t)4 << 20) + 2 * 131072);
    int* flags = (int*)(wsb + ((size_t)4 << 20) + 3 * 131072);
    int* cnt = (int*)(wsb + ((size_t)4 << 20) + 4 * 131072);

    kprep_p<<<512, 256, 0, stream>>>(P, Phi, Plo, cnt);
    kprep_e<<<8192, 256, 0, stream>>>(E, inv_e);
    kmain_fb<<<512, 256, 0, stream>>>(E, BS, Phi, Plo, CONF, inv_e, tau_ws, gd,
                                      out + 1, cnt, flags);
    krescore<<<64, 256, 0, stream>>>(E, P, BS, CONF, tau_ws, cnt, flags, gd, out + 1);
    kreduce<<<1, 1024, 0, stream>>>(gd, out);
  }
}

// Round 4
// 413.591 us; speedup vs baseline: 2.2273x; 2.2273x over previous
//
#include <hip/hip_runtime.h>
#include <math.h>

// GatedPrototypeDistillationLoss, MI355X gfx950 — bf16x3 MFMA, round 4.
// Round-3 post-mortem: dual-acc-bank digest interleave spilled to scratch
// (WRITE_SIZE 968 MB). Round 4 = round-2 loop structure (single acc bank,
// burst digest, proven 112 VGPR) + pre-split normalized E (Ehi/Elo in ws) so
// the A-path is pure global_load_lds: no in-loop bf16 conversion VALU, no
// global->reg->LDS round trip.

#define NB 32768
#define ND 512
#define NK 2048
#define TEMPR 0.07f
#define INV_T 14.285714285714286f
#define DX 1.4285714e-4f  // near-tie margin in x-domain (=1e-5 sim / T)

typedef unsigned short u16;
using bf16x8 = __attribute__((ext_vector_type(8))) short;
using f32x16 = __attribute__((ext_vector_type(16))) float;

__device__ inline u16 bf_hi(float x) {  // fp32 -> bf16 bits, RNE
  unsigned u = __float_as_uint(x);
  u = u + 0x7FFFu + ((u >> 16) & 1u);
  return (u16)(u >> 16);
}
__device__ inline float bf_tof(u16 h) {
  return __uint_as_float(((unsigned)h) << 16);
}
__device__ inline void gload_lds16(const void* g, void* l) {
  __builtin_amdgcn_global_load_lds((const __attribute__((address_space(1))) void*)g,
                                   (__attribute__((address_space(3))) void*)l, 16, 0, 0);
}
#define MF(a, b, c) __builtin_amdgcn_mfma_f32_32x32x16_bf16((a), (b), (c), 0, 0, 0)

// ---------------- kernel 1: P -> normalized bf16 hi/lo; zero flag counter ----
__global__ __launch_bounds__(256) void kprep_p(const float* __restrict__ P,
                                               u16* __restrict__ Phi,
                                               u16* __restrict__ Plo,
                                               int* __restrict__ cnt) {
  if (blockIdx.x == 0 && threadIdx.x == 0) *cnt = 0;
  const int lane = threadIdx.x & 63, w = threadIdx.x >> 6;
  const int row = blockIdx.x * 4 + w;  // grid 512 -> 2048 rows
  const float4* pr = (const float4*)(P + (size_t)row * ND);
  float4 a = pr[lane], b = pr[lane + 64];
  float ss = a.x * a.x + a.y * a.y + a.z * a.z + a.w * a.w
           + b.x * b.x + b.y * b.y + b.z * b.z + b.w * b.w;
#pragma unroll
  for (int off = 32; off > 0; off >>= 1) ss += __shfl_xor(ss, off);
  const float inv = 1.0f / fmaxf(sqrtf(ss), 1e-12f);
  ushort4 h4, l4;
#define PCNV(dst_h, dst_l, f) { float n_ = (f) * inv; u16 hb_ = bf_hi(n_); \
  dst_h = hb_; dst_l = bf_hi(n_ - bf_tof(hb_)); }
  PCNV(h4.x, l4.x, a.x) PCNV(h4.y, l4.y, a.y) PCNV(h4.z, l4.z, a.z) PCNV(h4.w, l4.w, a.w)
  *(ushort4*)(Phi + (size_t)row * ND + lane * 4) = h4;
  *(ushort4*)(Plo + (size_t)row * ND + lane * 4) = l4;
  PCNV(h4.x, l4.x, b.x) PCNV(h4.y, l4.y, b.y) PCNV(h4.z, l4.z, b.z) PCNV(h4.w, l4.w, b.w)
  *(ushort4*)(Phi + (size_t)row * ND + (lane + 64) * 4) = h4;
  *(ushort4*)(Plo + (size_t)row * ND + (lane + 64) * 4) = l4;
}

// ---------------- kernel 2 (fast): E -> normalized bf16 hi/lo ----------------
__global__ __launch_bounds__(256) void kprep_e2(const float* __restrict__ E,
                                                u16* __restrict__ Ehi,
                                                u16* __restrict__ Elo) {
  const int lane = threadIdx.x & 63, w = threadIdx.x >> 6;
  const int row = blockIdx.x * 4 + w;  // grid 8192 -> 32768 rows
  const float4* er = (const float4*)(E + (size_t)row * ND);
  float4 a = er[lane], b = er[lane + 64];
  float ss = a.x * a.x + a.y * a.y + a.z * a.z + a.w * a.w
           + b.x * b.x + b.y * b.y + b.z * b.z + b.w * b.w;
#pragma unroll
  for (int off = 32; off > 0; off >>= 1) ss += __shfl_xor(ss, off);
  const float inv = 1.0f / fmaxf(sqrtf(ss), 1e-12f);
  ushort4 h4, l4;
  PCNV(h4.x, l4.x, a.x) PCNV(h4.y, l4.y, a.y) PCNV(h4.z, l4.z, a.z) PCNV(h4.w, l4.w, a.w)
  *(ushort4*)(Ehi + (size_t)row * ND + lane * 4) = h4;
  *(ushort4*)(Elo + (size_t)row * ND + lane * 4) = l4;
  PCNV(h4.x, l4.x, b.x) PCNV(h4.y, l4.y, b.y) PCNV(h4.z, l4.z, b.z) PCNV(h4.w, l4.w, b.w)
  *(ushort4*)(Ehi + (size_t)row * ND + (lane + 64) * 4) = h4;
  *(ushort4*)(Elo + (size_t)row * ND + (lane + 64) * 4) = l4;
}

// ---------------- kernel 2 (fallback): embedding inverse norms ----------------
__global__ __launch_bounds__(256) void kprep_e(const float* __restrict__ E,
                                               float* __restrict__ inv_e) {
  const int lane = threadIdx.x & 63, w = threadIdx.x >> 6;
  const int row = blockIdx.x * 4 + w;
  const float4* er = (const float4*)(E + (size_t)row * ND);
  float4 a = er[lane], b = er[lane + 64];
  float ss = a.x * a.x + a.y * a.y + a.z * a.z + a.w * a.w
           + b.x * b.x + b.y * b.y + b.z * b.z + b.w * b.w;
#pragma unroll
  for (int off = 32; off > 0; off >>= 1) ss += __shfl_xor(ss, off);
  if (lane == 0) inv_e[row] = 1.0f / fmaxf(sqrtf(ss), 1e-12f);
}
#undef PCNV

// online update: x-domain logit, fixed offset; near-tie flag per slot bit
#define UPDV(r, vv, pp) { \
  float x_ = fmaf((vv), INV_T, -INV_T); \
  float e_ = __expf(x_); \
  sS[r] += e_; uS[r] = fmaf(x_, e_, uS[r]); \
  float d_ = x_ - mx[r]; \
  bool up_ = d_ > 0.0f; \
  bool nr_ = fabsf(d_) < DX; \
  mx[r] = up_ ? x_ : mx[r]; \
  ix[r] = up_ ? (pp) : ix[r]; \
  unsigned b_ = 1u << (r); \
  fl = (up_ ? (fl & ~b_) : fl) | (nr_ ? b_ : 0u); }

// ====== kernel 3 (fast): round-2 loop, A & B both pure global_load_lds ======
__global__ __launch_bounds__(256, 2) void kmain_v4(
    const float* __restrict__ BS,
    const u16* __restrict__ PhiG, const u16* __restrict__ PloG,
    const u16* __restrict__ EhiG, const u16* __restrict__ EloG,
    const float* __restrict__ CONF,
    float* __restrict__ tau_ws, float* __restrict__ gd, float* __restrict__ gate_out,
    int* __restrict__ cnt, int* __restrict__ flags) {
  __shared__ u16 Ahi[2][2048], Alo[2][2048];   // 64 rows x 32 d, dbuf
  __shared__ u16 Bhi[2][8192], Blo[2][8192];   // 256 protos x 32 d, dbuf

  const int t = threadIdx.x;
  const int lane = t & 63;
  const int w = t >> 6, wr = w >> 1, wc = w & 1;
  const int c = lane & 31, h = lane >> 5;
  const int swz = (blockIdx.x & 7) * 64 + (blockIdx.x >> 3);  // XCD swizzle (512=8*64)
  const int row0 = swz * 64;

  // A staging: thread t -> LDS slot t (linear dest), pre-swizzled global source
  const int arow_s = t >> 2, agp = t & 3;
  const int agsrc = agp ^ ((arow_s >> 1) & 3);
  const u16* EhiR = EhiG + (size_t)(row0 + arow_s) * ND + agsrc * 8;
  const u16* EloR = EloG + (size_t)(row0 + arow_s) * ND + agsrc * 8;

  // B staging per-instruction source offsets (pre-swizzled)
  int boff[4];
#pragma unroll
  for (int i = 0; i < 4; ++i) {
    int slot = w * 256 + i * 64 + lane;
    int rb = slot >> 2, gpb = slot & 3;
    int gsb = gpb ^ ((rb >> 1) & 3);
    boff[i] = rb * ND + gsb * 8;
  }

  // fragment-read constants
  const int arow4 = (wr * 32 + c) * 4;
  const int axor = ((wr * 32 + c) >> 1) & 3;
  const int bxor = (c >> 1) & 3;
  const int brow4 = (wc * 128 + c) * 4;

  f32x16 acc0, acc1, acc2, acc3;
#pragma unroll
  for (int i = 0; i < 16; ++i) { acc0[i] = 0.f; acc1[i] = 0.f; acc2[i] = 0.f; acc3[i] = 0.f; }
  float sS[16], uS[16], mx[16];
  int ix[16];
  unsigned fl = 0;
#pragma unroll
  for (int r = 0; r < 16; ++r) { sS[r] = 0.f; uS[r] = 0.f; mx[r] = -3.0e38f; ix[r] = 0; }

#define SB4(off, nx) { \
  _Pragma("unroll") \
  for (int i = 0; i < 4; ++i) { \
    gload_lds16(PhiG + (off) + boff[i], &Bhi[nx][(w * 256 + i * 64) * 8]); \
    gload_lds16(PloG + (off) + boff[i], &Blo[nx][(w * 256 + i * 64) * 8]); \
  } }
#define SA4(col, nx) { \
  gload_lds16(EhiR + (col), &Ahi[nx][t * 8]); \
  gload_lds16(EloR + (col), &Alo[nx][t * 8]); }

#define KS4(ks) { \
  const int ag_ = 2 * (ks) + h; \
  const int ao_ = (arow4 + (ag_ ^ axor)) * 8; \
  const bf16x8 ehi = *(const bf16x8*)&Ahi[cur][ao_]; \
  const bf16x8 elo = *(const bf16x8*)&Alo[cur][ao_]; \
  const int bo_ = (brow4 + (ag_ ^ bxor)) * 8; \
  const bf16x8 bh0 = *(const bf16x8*)&Bhi[cur][bo_]; \
  const bf16x8 bh1 = *(const bf16x8*)&Bhi[cur][bo_ + 1024]; \
  const bf16x8 bh2 = *(const bf16x8*)&Bhi[cur][bo_ + 2048]; \
  const bf16x8 bh3 = *(const bf16x8*)&Bhi[cur][bo_ + 3072]; \
  const bf16x8 bl0 = *(const bf16x8*)&Blo[cur][bo_]; \
  const bf16x8 bl1 = *(const bf16x8*)&Blo[cur][bo_ + 1024]; \
  const bf16x8 bl2 = *(const bf16x8*)&Blo[cur][bo_ + 2048]; \
  const bf16x8 bl3 = *(const bf16x8*)&Blo[cur][bo_ + 3072]; \
  acc0 = MF(ehi, bh0, acc0); acc1 = MF(ehi, bh1, acc1); \
  acc2 = MF(ehi, bh2, acc2); acc3 = MF(ehi, bh3, acc3); \
  acc0 = MF(ehi, bl0, acc0); acc1 = MF(ehi, bl1, acc1); \
  acc2 = MF(ehi, bl2, acc2); acc3 = MF(ehi, bl3, acc3); \
  acc0 = MF(elo, bh0, acc0); acc1 = MF(elo, bh1, acc1); \
  acc2 = MF(elo, bh2, acc2); acc3 = MF(elo, bh3, acc3); }

  // prologue: stage step 0 into buffer 0
  SB4(0, 0);
  SA4(0, 0);
  __syncthreads();

  for (int step = 0; step < 128; ++step) {
    const int cur = step & 1, nxt = cur ^ 1;
    const int ns = (step < 127) ? step + 1 : 127;  // last-iter dup, never read
    SB4((ns >> 4) * (256 * ND) + (ns & 15) * 32, nxt);
    SA4((ns & 15) * 32, nxt);
    KS4(0);
    KS4(1);
    if ((step & 15) == 15) {  // burst digest of this kt tile (runs under the
      const int pidb = (step >> 4) * 256 + wc * 128 + c;  // in-flight loads)
#pragma unroll
      for (int r = 0; r < 16; ++r) {
        UPDV(r, acc0[r], pidb)
        UPDV(r, acc1[r], pidb + 32)
        UPDV(r, acc2[r], pidb + 64)
        UPDV(r, acc3[r], pidb + 96)
        acc0[r] = 0.f; acc1[r] = 0.f; acc2[r] = 0.f; acc3[r] = 0.f;
      }
    }
    __syncthreads();  // drains global_load_lds for nxt
  }

  // ---- butterfly merge across the 32 proto-partition lanes ----
#pragma unroll
  for (int off = 1; off < 32; off <<= 1) {
    unsigned flo = __shfl_xor(fl, off);
    unsigned nfl = 0u;
#pragma unroll
    for (int r = 0; r < 16; ++r) {
      float mo = __shfl_xor(mx[r], off);
      float so = __shfl_xor(sS[r], off);
      float uo = __shfl_xor(uS[r], off);
      int io = __shfl_xor(ix[r], off);
      sS[r] += so; uS[r] += uo;
      float d = mo - mx[r];
      bool up = d > 0.0f;
      bool nr = fabsf(d) < DX;
      bool f0 = (fl >> r) & 1u, f1 = (flo >> r) & 1u;
      bool fw = (up ? f1 : f0) || nr;
      mx[r] = up ? mo : mx[r];
      ix[r] = up ? io : ix[r];
      nfl |= fw ? (1u << r) : 0u;
    }
    fl = nfl;
  }

  // ---- cross-wave (wc) merge via LDS (alias onto Ahi, compute done) ----
  float* mg = (float*)&Ahi[0][0];  // [wr][wc][32 rows][6]
  if (c == 0) {
#pragma unroll
    for (int r = 0; r < 16; ++r) {
      int rowl = (r & 3) + 8 * (r >> 2) + 4 * h;
      int base = ((wr * 2 + wc) * 32 + rowl) * 6;
      mg[base + 0] = mx[r];
      mg[base + 1] = sS[r];
      mg[base + 2] = uS[r];
      mg[base + 3] = __int_as_float(ix[r]);
      mg[base + 4] = ((fl >> r) & 1u) ? 1.0f : 0.0f;
    }
  }
  __syncthreads();

  if ((w & 1) == 0 && lane < 32) {
    const int rowl = lane;
    const int b0 = ((wr * 2 + 0) * 32 + rowl) * 6;
    const int b1 = ((wr * 2 + 1) * 32 + rowl) * 6;
    float m0 = mg[b0], s0 = mg[b0 + 1], u0 = mg[b0 + 2];
    int i0 = __float_as_int(mg[b0 + 3]);
    bool f0 = mg[b0 + 4] != 0.0f;
    float m1 = mg[b1], s1 = mg[b1 + 1], u1 = mg[b1 + 2];
    int i1 = __float_as_int(mg[b1 + 3]);
    bool f1 = mg[b1 + 4] != 0.0f;
    float d = m1 - m0;
    bool up = d > 0.0f;
    float m = up ? m1 : m0;
    int idx = up ? i1 : i0;
    bool flg = (up ? f1 : f0) || (fabsf(d) < DX);
    float s = s0 + s1, u = u0 + u1;

    float ent = logf(s) - u / s;  // = lse - E[logit]
    float tau = 0.5f - 0.2f * (ent * (1.0f / (7.6246190071f + 1e-8f)));
    float simmax = fmaf(m, TEMPR, 1.0f);  // m is (sim-1)/T
    float dist = sqrtf(fmaxf(2.0f - 2.0f * simmax, 0.0f));
    int grow = row0 + wr * 32 + rowl;
    float g = CONF[idx] / (1.0f + __expf(-(BS[grow] - tau) * INV_T));
    gate_out[grow] = g;
    gd[grow] = g * dist;
    tau_ws[grow] = tau;
    if (flg) {
      int p = atomicAdd(cnt, 1);
      flags[p] = grow;
    }
  }
}

// ================= kernel 3 (fallback): round-2 kmain =======================
__global__ __launch_bounds__(256, 2) void kmain_fb(
    const float* __restrict__ E, const float* __restrict__ BS,
    const u16* __restrict__ Phi, const u16* __restrict__ Plo,
    const float* __restrict__ CONF, const float* __restrict__ inv_e,
    float* __restrict__ tau_ws, float* __restrict__ gd, float* __restrict__ gate_out,
    int* __restrict__ cnt, int* __restrict__ flags) {
  __shared__ u16 Ahi[2][2048], Alo[2][2048];
  __shared__ u16 Bhi[2][8192], Blo[2][8192];

  const int t = threadIdx.x;
  const int lane = t & 63;
  const int w = t >> 6, wr = w >> 1, wc = w & 1;
  const int c = lane & 31, h = lane >> 5;
  const int swz = (blockIdx.x & 7) * 64 + (blockIdx.x >> 3);
  const int row0 = swz * 64;

  const int arow_s = t >> 2, agp = t & 3;
  const int agsrc = agp ^ ((arow_s >> 1) & 3);
  const float inve = inv_e[row0 + arow_s];
  const float* Asrc = E + (size_t)(row0 + arow_s) * ND + agsrc * 8;

  int boff[4];
#pragma unroll
  for (int i = 0; i < 4; ++i) {
    int slot = w * 256 + i * 64 + lane;
    int rb = slot >> 2, gpb = slot & 3;
    int gsb = gpb ^ ((rb >> 1) & 3);
    boff[i] = rb * ND + gsb * 8;
  }

  const int arow4 = (wr * 32 + c) * 4;
  const int axor = ((wr * 32 + c) >> 1) & 3;
  const int bxor = (c >> 1) & 3;
  const int brow4 = (wc * 128 + c) * 4;

  f32x16 acc0, acc1, acc2, acc3;
#pragma unroll
  for (int i = 0; i < 16; ++i) { acc0[i] = 0.f; acc1[i] = 0.f; acc2[i] = 0.f; acc3[i] = 0.f; }
  float sS[16], uS[16], mx[16];
  int ix[16];
  unsigned fl = 0;
#pragma unroll
  for (int r = 0; r < 16; ++r) { sS[r] = 0.f; uS[r] = 0.f; mx[r] = -3.0e38f; ix[r] = 0; }

#define STAGE_B(tkt, tdt, nx) { \
  const int ko_ = (tkt) * 256 * ND + (tdt) * 32; \
  _Pragma("unroll") \
  for (int i = 0; i < 4; ++i) { \
    gload_lds16(Phi + ko_ + boff[i], &Bhi[nx][(w * 256 + i * 64) * 8]); \
    gload_lds16(Plo + ko_ + boff[i], &Blo[nx][(w * 256 + i * 64) * 8]); \
  } }
#define LOAD_A(tdt) { const float4* ap_ = (const float4*)(Asrc + (tdt) * 32); \
  a0 = ap_[0]; a1 = ap_[1]; }
#define ACNV(j, f) { float n_ = (f) * inve; u16 hb_ = bf_hi(n_); \
  hv[j] = (short)hb_; lv[j] = (short)bf_hi(n_ - bf_tof(hb_)); }
#define WRITE_A(nx) { bf16x8 hv, lv; \
  ACNV(0, a0.x) ACNV(1, a0.y) ACNV(2, a0.z) ACNV(3, a0.w) \
  ACNV(4, a1.x) ACNV(5, a1.y) ACNV(6, a1.z) ACNV(7, a1.w) \
  *(bf16x8*)&Ahi[nx][t * 8] = hv; *(bf16x8*)&Alo[nx][t * 8] = lv; }
#define KSTEP(ks) { \
  const int ag_ = 2 * (ks) + h; \
  const int ao_ = (arow4 + (ag_ ^ axor)) * 8; \
  const bf16x8 ehi = *(const bf16x8*)&Ahi[cur][ao_]; \
  const bf16x8 elo = *(const bf16x8*)&Alo[cur][ao_]; \
  const int bo_ = (brow4 + (ag_ ^ bxor)) * 8; \
  const bf16x8 bh0 = *(const bf16x8*)&Bhi[cur][bo_]; \
  const bf16x8 bh1 = *(const bf16x8*)&Bhi[cur][bo_ + 1024]; \
  const bf16x8 bh2 = *(const bf16x8*)&Bhi[cur][bo_ + 2048]; \
  const bf16x8 bh3 = *(const bf16x8*)&Bhi[cur][bo_ + 3072]; \
  const bf16x8 bl0 = *(const bf16x8*)&Blo[cur][bo_]; \
  const bf16x8 bl1 = *(const bf16x8*)&Blo[cur][bo_ + 1024]; \
  const bf16x8 bl2 = *(const bf16x8*)&Blo[cur][bo_ + 2048]; \
  const bf16x8 bl3 = *(const bf16x8*)&Blo[cur][bo_ + 3072]; \
  acc0 = MF(ehi, bh0, acc0); acc1 = MF(ehi, bh1, acc1); \
  acc2 = MF(ehi, bh2, acc2); acc3 = MF(ehi, bh3, acc3); \
  acc0 = MF(ehi, bl0, acc0); acc1 = MF(ehi, bl1, acc1); \
  acc2 = MF(ehi, bl2, acc2); acc3 = MF(ehi, bl3, acc3); \
  acc0 = MF(elo, bh0, acc0); acc1 = MF(elo, bh1, acc1); \
  acc2 = MF(elo, bh2, acc2); acc3 = MF(elo, bh3, acc3); }

  float4 a0, a1;
  STAGE_B(0, 0, 0);
  LOAD_A(0);
  WRITE_A(0);
  __syncthreads();

  for (int step = 0; step < 128; ++step) {
    const int cur = step & 1, nxt = cur ^ 1;
    const int ns = (step < 127) ? step + 1 : 127;
    STAGE_B(ns >> 4, ns & 15, nxt);
    LOAD_A(ns & 15);
    KSTEP(0);
    KSTEP(1);
    WRITE_A(nxt);
    if ((step & 15) == 15) {
      const int pidb = (step >> 4) * 256 + wc * 128 + c;
#pragma unroll
      for (int r = 0; r < 16; ++r) {
        UPDV(r, acc0[r], pidb)
        UPDV(r, acc1[r], pidb + 32)
        UPDV(r, acc2[r], pidb + 64)
        UPDV(r, acc3[r], pidb + 96)
        acc0[r] = 0.f; acc1[r] = 0.f; acc2[r] = 0.f; acc3[r] = 0.f;
      }
    }
    __syncthreads();
  }

#pragma unroll
  for (int off = 1; off < 32; off <<= 1) {
    unsigned flo = __shfl_xor(fl, off);
    unsigned nfl = 0u;
#pragma unroll
    for (int r = 0; r < 16; ++r) {
      float mo = __shfl_xor(mx[r], off);
      float so = __shfl_xor(sS[r], off);
      float uo = __shfl_xor(uS[r], off);
      int io = __shfl_xor(ix[r], off);
      sS[r] += so; uS[r] += uo;
      float d = mo - mx[r];
      bool up = d > 0.0f;
      bool nr = fabsf(d) < DX;
      bool f0 = (fl >> r) & 1u, f1 = (flo >> r) & 1u;
      bool fw = (up ? f1 : f0) || nr;
      mx[r] = up ? mo : mx[r];
      ix[r] = up ? io : ix[r];
      nfl |= fw ? (1u << r) : 0u;
    }
    fl = nfl;
  }

  float* mg = (float*)&Ahi[0][0];
  if (c == 0) {
#pragma unroll
    for (int r = 0; r < 16; ++r) {
      int rowl = (r & 3) + 8 * (r >> 2) + 4 * h;
      int base = ((wr * 2 + wc) * 32 + rowl) * 6;
      mg[base + 0] = mx[r];
      mg[base + 1] = sS[r];
      mg[base + 2] = uS[r];
      mg[base + 3] = __int_as_float(ix[r]);
      mg[base + 4] = ((fl >> r) & 1u) ? 1.0f : 0.0f;
    }
  }
  __syncthreads();

  if ((w & 1) == 0 && lane < 32) {
    const int rowl = lane;
    const int b0 = ((wr * 2 + 0) * 32 + rowl) * 6;
    const int b1 = ((wr * 2 + 1) * 32 + rowl) * 6;
    float m0 = mg[b0], s0 = mg[b0 + 1], u0 = mg[b0 + 2];
    int i0 = __float_as_int(mg[b0 + 3]);
    bool f0 = mg[b0 + 4] != 0.0f;
    float m1 = mg[b1], s1 = mg[b1 + 1], u1 = mg[b1 + 2];
    int i1 = __float_as_int(mg[b1 + 3]);
    bool f1 = mg[b1 + 4] != 0.0f;
    float d = m1 - m0;
    bool up = d > 0.0f;
    float m = up ? m1 : m0;
    int idx = up ? i1 : i0;
    bool flg = (up ? f1 : f0) || (fabsf(d) < DX);
    float s = s0 + s1, u = u0 + u1;
    float ent = logf(s) - u / s;
    float tau = 0.5f - 0.2f * (ent * (1.0f / (7.6246190071f + 1e-8f)));
    float simmax = fmaf(m, TEMPR, 1.0f);
    float dist = sqrtf(fmaxf(2.0f - 2.0f * simmax, 0.0f));
    int grow = row0 + wr * 32 + rowl;
    float g = CONF[idx] / (1.0f + __expf(-(BS[grow] - tau) * INV_T));
    gate_out[grow] = g;
    gd[grow] = g * dist;
    tau_ws[grow] = tau;
    if (flg) {
      int p = atomicAdd(cnt, 1);
      flags[p] = grow;
    }
  }
}

// ---------------- kernel 4: fp32 rescore of near-tie rows ----------------
__global__ __launch_bounds__(256) void krescore(
    const float* __restrict__ E, const float* __restrict__ P,
    const float* __restrict__ BS, const float* __restrict__ CONF,
    const float* __restrict__ tau_ws, const int* __restrict__ cnt,
    const int* __restrict__ flags, float* __restrict__ gd,
    float* __restrict__ gate_out) {
  __shared__ float en[512];
  __shared__ float red[256];
  __shared__ int redi[256];
  __shared__ float sinv;
  const int n = *cnt;
  const int t = threadIdx.x;
  for (int j = blockIdx.x; j < n; j += gridDim.x) {
    const int row = flags[j];
    float2 v = ((const float2*)(E + (size_t)row * ND))[t];
    red[t] = v.x * v.x + v.y * v.y;
    __syncthreads();
    for (int o = 128; o > 0; o >>= 1) {
      if (t < o) red[t] += red[t + o];
      __syncthreads();
    }
    if (t == 0) sinv = 1.0f / fmaxf(sqrtf(red[0]), 1e-12f);
    __syncthreads();
    en[2 * t] = v.x * sinv;
    en[2 * t + 1] = v.y * sinv;
    __syncthreads();
    float best = -3.0e38f;
    int bidx = 0;
    for (int k = 0; k < 8; ++k) {
      const int p = k * 256 + t;
      const float4* pr = (const float4*)(P + (size_t)p * ND);
      float dot = 0.f, pp = 0.f;
      for (int i = 0; i < 128; ++i) {
        float4 a = pr[i];
        float4 e4 = ((const float4*)en)[i];
        dot = fmaf(a.x, e4.x, dot); dot = fmaf(a.y, e4.y, dot);
        dot = fmaf(a.z, e4.z, dot); dot = fmaf(a.w, e4.w, dot);
        pp = fmaf(a.x, a.x, pp); pp = fmaf(a.y, a.y, pp);
        pp = fmaf(a.z, a.z, pp); pp = fmaf(a.w, a.w, pp);
      }
      float sim = dot / fmaxf(sqrtf(pp), 1e-12f);
      if (sim > best) { best = sim; bidx = p; }
    }
    red[t] = best;
    redi[t] = bidx;
    __syncthreads();
    if (t == 0) {
      float bb = red[0];
      int bi = redi[0];
      for (int i = 1; i < 256; ++i) {
        float vv = red[i];
        int ii = redi[i];
        if (vv > bb || (vv == bb && ii < bi)) { bb = vv; bi = ii; }
      }
      float tau = tau_ws[row];
      float dist = sqrtf(fmaxf(2.0f - 2.0f * bb, 0.0f));
      float g = CONF[bi] / (1.0f + __expf(-(BS[row] - tau) * INV_T));
      gate_out[row] = g;
      gd[row] = g * dist;
    }
    __syncthreads();
  }
}

// ---------------- kernel 5: deterministic mean ----------------
__global__ __launch_bounds__(1024) void kreduce(const float* __restrict__ gd,
                                                float* __restrict__ out0) {
  __shared__ float red[1024];
  const int t = threadIdx.x;
  float s = 0.f;
  const float4* g4 = (const float4*)gd;
  for (int i = t; i < 8192; i += 1024) {
    float4 v = g4[i];
    s += (v.x + v.y) + (v.z + v.w);
  }
  red[t] = s;
  __syncthreads();
  for (int off = 512; off > 0; off >>= 1) {
    if (t < off) red[t] += red[t + off];
    __syncthreads();
  }
  if (t == 0) out0[0] = red[0] * (1.0f / 32768.0f);
}

extern "C" void kernel_launch(void* const* d_in, const int* in_sizes, int n_in,
                              void* d_out, int out_size, void* d_ws, size_t ws_size,
                              hipStream_t stream) {
  const float* E = (const float*)d_in[0];
  const float* BS = (const float*)d_in[1];
  const float* P = (const float*)d_in[2];
  const float* CONF = (const float*)d_in[3];
  float* out = (float*)d_out;  // [0]=L_proto, [1..32768]=gate

  char* wsb = (char*)d_ws;
  const bool fast = ws_size >= (size_t)69 * 1024 * 1024;

  if (fast) {
    u16* Phi = (u16*)wsb;                                   // 2 MB @ 0
    u16* Plo = (u16*)(wsb + ((size_t)2 << 20));             // 2 MB @ 2M
    u16* Ehi = (u16*)(wsb + ((size_t)4 << 20));             // 32 MB @ 4M
    u16* Elo = (u16*)(wsb + ((size_t)36 << 20));            // 32 MB @ 36M
    float* tau_ws = (float*)(wsb + ((size_t)68 << 20));     // 128 KB
    float* gd = (float*)(wsb + ((size_t)68 << 20) + 131072);
    int* flags = (int*)(wsb + ((size_t)68 << 20) + 2 * 131072);
    int* cnt = (int*)(wsb + ((size_t)68 << 20) + 3 * 131072);

    kprep_p<<<512, 256, 0, stream>>>(P, Phi, Plo, cnt);
    kprep_e2<<<8192, 256, 0, stream>>>(E, Ehi, Elo);
    kmain_v4<<<512, 256, 0, stream>>>(BS, Phi, Plo, Ehi, Elo, CONF, tau_ws, gd,
                                      out + 1, cnt, flags);
    krescore<<<64, 256, 0, stream>>>(E, P, BS, CONF, tau_ws, cnt, flags, gd, out + 1);
    kreduce<<<1, 1024, 0, stream>>>(gd, out);
  } else {
    u16* Phi = (u16*)wsb;
    u16* Plo = (u16*)(wsb + ((size_t)2 << 20));
    float* inv_e = (float*)(wsb + ((size_t)4 << 20));
    float* tau_ws = (float*)(wsb + ((size_t)4 << 20) + 131072);
    float* gd = (float*)(wsb + ((size_t)4 << 20) + 2 * 131072);
    int* flags = (int*)(wsb + ((size_t)4 << 20) + 3 * 131072);
    int* cnt = (int*)(wsb + ((size_t)4 << 20) + 4 * 131072);

    kprep_p<<<512, 256, 0, stream>>>(P, Phi, Plo, cnt);
    kprep_e<<<8192, 256, 0, stream>>>(E, inv_e);
    kmain_fb<<<512, 256, 0, stream>>>(E, BS, Phi, Plo, CONF, inv_e, tau_ws, gd,
                                      out + 1, cnt, flags);
    krescore<<<64, 256, 0, stream>>>(E, P, BS, CONF, tau_ws, cnt, flags, gd, out + 1);
    kreduce<<<1, 1024, 0, stream>>>(gd, out);
  }
}

// Round 5
// 404.493 us; speedup vs baseline: 2.2774x; 1.0225x over previous
//
#include <hip/hip_runtime.h>
#include <math.h>

// GatedPrototypeDistillationLoss, MI355X gfx950 — round 5.
//  * kmain_v5: counted-vmcnt pipeline (T4): per step
//      ds_read frags -> MFMA(ks0) -> lgkmcnt(0)+s_barrier -> stage(t+2)
//      -> MFMA(ks1)[+digest] -> vmcnt(10)+s_barrier
//    (no per-step vmcnt(0) drain; loads get ~1.5 steps of flight)
//  * exact top-2 (m1,m2,idx) tracking replaces running-max near-tie flags:
//    flag iff final gap < DX  => ~30 rescore rows instead of ~1000.

#define NB 32768
#define ND 512
#define NK 2048
#define TEMPR 0.07f
#define INV_T 14.285714285714286f
#define DX 1.4285714e-4f  // near-tie margin in x-domain (=1e-5 sim / T)

typedef unsigned short u16;
using bf16x8 = __attribute__((ext_vector_type(8))) short;
using f32x16 = __attribute__((ext_vector_type(16))) float;

__device__ inline u16 bf_hi(float x) {  // fp32 -> bf16 bits, RNE
  unsigned u = __float_as_uint(x);
  u = u + 0x7FFFu + ((u >> 16) & 1u);
  return (u16)(u >> 16);
}
__device__ inline float bf_tof(u16 h) {
  return __uint_as_float(((unsigned)h) << 16);
}
__device__ inline void gload_lds16(const void* g, void* l) {
  __builtin_amdgcn_global_load_lds((const __attribute__((address_space(1))) void*)g,
                                   (__attribute__((address_space(3))) void*)l, 16, 0, 0);
}
#define MF(a, b, c) __builtin_amdgcn_mfma_f32_32x32x16_bf16((a), (b), (c), 0, 0, 0)

#define WAIT_LGKM0 { asm volatile("s_waitcnt lgkmcnt(0)" ::: "memory"); \
                     __builtin_amdgcn_sched_barrier(0); }
#define WAIT_VM10  { asm volatile("s_waitcnt vmcnt(10)" ::: "memory"); \
                     __builtin_amdgcn_sched_barrier(0); }
#define SBAR       { __builtin_amdgcn_s_barrier(); \
                     __builtin_amdgcn_sched_barrier(0); }

// ---------------- kernel 1: P -> normalized bf16 hi/lo; zero flag counter ----
__global__ __launch_bounds__(256) void kprep_p(const float* __restrict__ P,
                                               u16* __restrict__ Phi,
                                               u16* __restrict__ Plo,
                                               int* __restrict__ cnt) {
  if (blockIdx.x == 0 && threadIdx.x == 0) *cnt = 0;
  const int lane = threadIdx.x & 63, w = threadIdx.x >> 6;
  const int row = blockIdx.x * 4 + w;  // grid 512 -> 2048 rows
  const float4* pr = (const float4*)(P + (size_t)row * ND);
  float4 a = pr[lane], b = pr[lane + 64];
  float ss = a.x * a.x + a.y * a.y + a.z * a.z + a.w * a.w
           + b.x * b.x + b.y * b.y + b.z * b.z + b.w * b.w;
#pragma unroll
  for (int off = 32; off > 0; off >>= 1) ss += __shfl_xor(ss, off);
  const float inv = 1.0f / fmaxf(sqrtf(ss), 1e-12f);
  ushort4 h4, l4;
#define PCNV(dst_h, dst_l, f) { float n_ = (f) * inv; u16 hb_ = bf_hi(n_); \
  dst_h = hb_; dst_l = bf_hi(n_ - bf_tof(hb_)); }
  PCNV(h4.x, l4.x, a.x) PCNV(h4.y, l4.y, a.y) PCNV(h4.z, l4.z, a.z) PCNV(h4.w, l4.w, a.w)
  *(ushort4*)(Phi + (size_t)row * ND + lane * 4) = h4;
  *(ushort4*)(Plo + (size_t)row * ND + lane * 4) = l4;
  PCNV(h4.x, l4.x, b.x) PCNV(h4.y, l4.y, b.y) PCNV(h4.z, l4.z, b.z) PCNV(h4.w, l4.w, b.w)
  *(ushort4*)(Phi + (size_t)row * ND + (lane + 64) * 4) = h4;
  *(ushort4*)(Plo + (size_t)row * ND + (lane + 64) * 4) = l4;
}

// ---------------- kernel 2: E -> normalized bf16 hi/lo ----------------
__global__ __launch_bounds__(256) void kprep_e2(const float* __restrict__ E,
                                                u16* __restrict__ Ehi,
                                                u16* __restrict__ Elo) {
  const int lane = threadIdx.x & 63, w = threadIdx.x >> 6;
  const int row = blockIdx.x * 4 + w;  // grid 8192 -> 32768 rows
  const float4* er = (const float4*)(E + (size_t)row * ND);
  float4 a = er[lane], b = er[lane + 64];
  float ss = a.x * a.x + a.y * a.y + a.z * a.z + a.w * a.w
           + b.x * b.x + b.y * b.y + b.z * b.z + b.w * b.w;
#pragma unroll
  for (int off = 32; off > 0; off >>= 1) ss += __shfl_xor(ss, off);
  const float inv = 1.0f / fmaxf(sqrtf(ss), 1e-12f);
  ushort4 h4, l4;
  PCNV(h4.x, l4.x, a.x) PCNV(h4.y, l4.y, a.y) PCNV(h4.z, l4.z, a.z) PCNV(h4.w, l4.w, a.w)
  *(ushort4*)(Ehi + (size_t)row * ND + lane * 4) = h4;
  *(ushort4*)(Elo + (size_t)row * ND + lane * 4) = l4;
  PCNV(h4.x, l4.x, b.x) PCNV(h4.y, l4.y, b.y) PCNV(h4.z, l4.z, b.z) PCNV(h4.w, l4.w, b.w)
  *(ushort4*)(Ehi + (size_t)row * ND + (lane + 64) * 4) = h4;
  *(ushort4*)(Elo + (size_t)row * ND + (lane + 64) * 4) = l4;
}
#undef PCNV

// online update with exact top-2 tracking (x-domain logit, fixed offset)
#define UPD2(r, vv, pp) { \
  float x_ = fmaf((vv), INV_T, -INV_T); \
  float e_ = __expf(x_); \
  sS[r] += e_; uS[r] = fmaf(x_, e_, uS[r]); \
  bool u1_ = x_ > m1[r]; \
  float lo_ = u1_ ? m1[r] : x_; \
  m2[r] = fmaxf(m2[r], lo_); \
  m1[r] = u1_ ? x_ : m1[r]; \
  ix[r] = u1_ ? (pp) : ix[r]; }

// ====== kernel 3: MFMA GEMM, counted-vmcnt pipeline, top-2 softmax ======
__global__ __launch_bounds__(256, 2) void kmain_v5(
    const float* __restrict__ BS,
    const u16* __restrict__ PhiG, const u16* __restrict__ PloG,
    const u16* __restrict__ EhiG, const u16* __restrict__ EloG,
    const float* __restrict__ CONF,
    float* __restrict__ tau_ws, float* __restrict__ gd, float* __restrict__ gate_out,
    int* __restrict__ cnt, int* __restrict__ flags) {
  __shared__ u16 Ahi[2][2048], Alo[2][2048];   // 64 rows x 32 d, dbuf
  __shared__ u16 Bhi[2][8192], Blo[2][8192];   // 256 protos x 32 d, dbuf

  const int t = threadIdx.x;
  const int lane = t & 63;
  const int w = t >> 6, wr = w >> 1, wc = w & 1;
  const int c = lane & 31, h = lane >> 5;
  const int swz = (blockIdx.x & 7) * 64 + (blockIdx.x >> 3);  // XCD swizzle (512=8*64)
  const int row0 = swz * 64;

  // A staging: thread t -> LDS slot t (linear dest), pre-swizzled global source
  const int arow_s = t >> 2, agp = t & 3;
  const int agsrc = agp ^ ((arow_s >> 1) & 3);
  const u16* EhiR = EhiG + (size_t)(row0 + arow_s) * ND + agsrc * 8;
  const u16* EloR = EloG + (size_t)(row0 + arow_s) * ND + agsrc * 8;

  // B staging per-instruction source offsets (pre-swizzled)
  int boff[4];
#pragma unroll
  for (int i = 0; i < 4; ++i) {
    int slot = w * 256 + i * 64 + lane;
    int rb = slot >> 2, gpb = slot & 3;
    int gsb = gpb ^ ((rb >> 1) & 3);
    boff[i] = rb * ND + gsb * 8;
  }

  // fragment-read constants
  const int arow4 = (wr * 32 + c) * 4;
  const int axor = ((wr * 32 + c) >> 1) & 3;
  const int bxor = (c >> 1) & 3;
  const int brow4 = (wc * 128 + c) * 4;
  const int ao0 = (arow4 + ((0 + h) ^ axor)) * 8;  // ks=0
  const int ao1 = (arow4 + ((2 + h) ^ axor)) * 8;  // ks=1
  const int bo0 = (brow4 + ((0 + h) ^ bxor)) * 8;
  const int bo1 = (brow4 + ((2 + h) ^ bxor)) * 8;

  f32x16 acc0, acc1, acc2, acc3;
#pragma unroll
  for (int i = 0; i < 16; ++i) { acc0[i] = 0.f; acc1[i] = 0.f; acc2[i] = 0.f; acc3[i] = 0.f; }
  float sS[16], uS[16], m1[16], m2[16];
  int ix[16];
#pragma unroll
  for (int r = 0; r < 16; ++r) {
    sS[r] = 0.f; uS[r] = 0.f; m1[r] = -3.0e38f; m2[r] = -3.0e38f; ix[r] = 0;
  }

#define SB5(off, nx) { \
  _Pragma("unroll") \
  for (int i = 0; i < 4; ++i) { \
    gload_lds16(PhiG + (off) + boff[i], &Bhi[nx][(w * 256 + i * 64) * 8]); \
    gload_lds16(PloG + (off) + boff[i], &Blo[nx][(w * 256 + i * 64) * 8]); \
  } }
#define SA5(col, nx) { \
  gload_lds16(EhiR + (col), &Ahi[nx][t * 8]); \
  gload_lds16(EloR + (col), &Alo[nx][t * 8]); }

  // prologue: stage step 0 -> buf0, step 1 -> buf1; wait step0 only
  SB5(0, 0);
  SA5(0, 0);
  SB5(32, 1);
  SA5(32, 1);
  WAIT_VM10;
  SBAR;

#pragma unroll 2
  for (int step = 0; step < 128; ++step) {
    const int cur = step & 1;
    // ---- phase R: all 20 fragment reads from buf[cur] ----
    const bf16x8 eh0 = *(const bf16x8*)&Ahi[cur][ao0];
    const bf16x8 el0 = *(const bf16x8*)&Alo[cur][ao0];
    const bf16x8 eh1 = *(const bf16x8*)&Ahi[cur][ao1];
    const bf16x8 el1 = *(const bf16x8*)&Alo[cur][ao1];
    const bf16x8 bh00 = *(const bf16x8*)&Bhi[cur][bo0];
    const bf16x8 bh01 = *(const bf16x8*)&Bhi[cur][bo0 + 1024];
    const bf16x8 bh02 = *(const bf16x8*)&Bhi[cur][bo0 + 2048];
    const bf16x8 bh03 = *(const bf16x8*)&Bhi[cur][bo0 + 3072];
    const bf16x8 bl00 = *(const bf16x8*)&Blo[cur][bo0];
    const bf16x8 bl01 = *(const bf16x8*)&Blo[cur][bo0 + 1024];
    const bf16x8 bl02 = *(const bf16x8*)&Blo[cur][bo0 + 2048];
    const bf16x8 bl03 = *(const bf16x8*)&Blo[cur][bo0 + 3072];
    const bf16x8 bh10 = *(const bf16x8*)&Bhi[cur][bo1];
    const bf16x8 bh11 = *(const bf16x8*)&Bhi[cur][bo1 + 1024];
    const bf16x8 bh12 = *(const bf16x8*)&Bhi[cur][bo1 + 2048];
    const bf16x8 bh13 = *(const bf16x8*)&Bhi[cur][bo1 + 3072];
    const bf16x8 bl10 = *(const bf16x8*)&Blo[cur][bo1];
    const bf16x8 bl11 = *(const bf16x8*)&Blo[cur][bo1 + 1024];
    const bf16x8 bl12 = *(const bf16x8*)&Blo[cur][bo1 + 2048];
    const bf16x8 bl13 = *(const bf16x8*)&Blo[cur][bo1 + 3072];

    // ---- MFMA ks=0 (frag regs for ks=0 die here) ----
    acc0 = MF(eh0, bh00, acc0); acc1 = MF(eh0, bh01, acc1);
    acc2 = MF(eh0, bh02, acc2); acc3 = MF(eh0, bh03, acc3);
    acc0 = MF(eh0, bl00, acc0); acc1 = MF(eh0, bl01, acc1);
    acc2 = MF(eh0, bl02, acc2); acc3 = MF(eh0, bl03, acc3);
    acc0 = MF(el0, bh00, acc0); acc1 = MF(el0, bh01, acc1);
    acc2 = MF(el0, bh02, acc2); acc3 = MF(el0, bh03, acc3);

    // ---- barrier 1: all waves done READING buf[cur]; no vmcnt drain ----
    WAIT_LGKM0;
    SBAR;

    // ---- phase S: stage step+2 into buf[cur] (flies across ~1.5 steps) ----
    const int ns = (step < 126) ? step + 2 : 127;  // tail dup, never read
    SB5((ns >> 4) * (256 * ND) + (ns & 15) * 32, cur);
    SA5((ns & 15) * 32, cur);

    // ---- MFMA ks=1 ----
    acc0 = MF(eh1, bh10, acc0); acc1 = MF(eh1, bh11, acc1);
    acc2 = MF(eh1, bh12, acc2); acc3 = MF(eh1, bh13, acc3);
    acc0 = MF(eh1, bl10, acc0); acc1 = MF(eh1, bl11, acc1);
    acc2 = MF(eh1, bl12, acc2); acc3 = MF(eh1, bl13, acc3);
    acc0 = MF(el1, bh10, acc0); acc1 = MF(el1, bh11, acc1);
    acc2 = MF(el1, bh12, acc2); acc3 = MF(el1, bh13, acc3);

    if ((step & 15) == 15) {  // kt-tile digest (overlaps in-flight stages)
      const int pidb = (step >> 4) * 256 + wc * 128 + c;
#pragma unroll
      for (int r = 0; r < 16; ++r) {
        UPD2(r, acc0[r], pidb)
        UPD2(r, acc1[r], pidb + 32)
        UPD2(r, acc2[r], pidb + 64)
        UPD2(r, acc3[r], pidb + 96)
        acc0[r] = 0.f; acc1[r] = 0.f; acc2[r] = 0.f; acc3[r] = 0.f;
      }
    }

    // ---- barrier 2: retire ONLY step t+1's 10 loads (counted vmcnt) ----
    WAIT_VM10;
    SBAR;
  }

  __syncthreads();  // full drain (tail dup-stages still write Ahi/Bhi)

  // ---- butterfly merge across the 32 proto-partition lanes ----
#pragma unroll
  for (int off = 1; off < 32; off <<= 1) {
#pragma unroll
    for (int r = 0; r < 16; ++r) {
      float m1o = __shfl_xor(m1[r], off);
      float m2o = __shfl_xor(m2[r], off);
      float so = __shfl_xor(sS[r], off);
      float uo = __shfl_xor(uS[r], off);
      int io = __shfl_xor(ix[r], off);
      sS[r] += so; uS[r] += uo;
      bool up = (m1o > m1[r]) || (m1o == m1[r] && io < ix[r]);
      float losr = (m1o > m1[r]) ? m1[r] : m1o;  // min(m1, m1o)
      m2[r] = fmaxf(fmaxf(m2[r], m2o), losr);
      m1[r] = fmaxf(m1[r], m1o);
      ix[r] = up ? io : ix[r];
    }
  }

  // ---- cross-wave (wc) merge via LDS (alias onto Ahi, compute done) ----
  float* mg = (float*)&Ahi[0][0];  // [wr][wc][32 rows][6]
  if (c == 0) {
#pragma unroll
    for (int r = 0; r < 16; ++r) {
      int rowl = (r & 3) + 8 * (r >> 2) + 4 * h;
      int base = ((wr * 2 + wc) * 32 + rowl) * 6;
      mg[base + 0] = m1[r];
      mg[base + 1] = sS[r];
      mg[base + 2] = uS[r];
      mg[base + 3] = __int_as_float(ix[r]);
      mg[base + 4] = m2[r];
    }
  }
  __syncthreads();

  if ((w & 1) == 0 && lane < 32) {
    const int rowl = lane;
    const int b0 = ((wr * 2 + 0) * 32 + rowl) * 6;
    const int b1 = ((wr * 2 + 1) * 32 + rowl) * 6;
    float m1a = mg[b0], s0 = mg[b0 + 1], u0 = mg[b0 + 2];
    int i0 = __float_as_int(mg[b0 + 3]);
    float m2a = mg[b0 + 4];
    float m1b = mg[b1], s1 = mg[b1 + 1], u1 = mg[b1 + 2];
    int i1 = __float_as_int(mg[b1 + 3]);
    float m2b = mg[b1 + 4];

    bool up = (m1b > m1a) || (m1b == m1a && i1 < i0);
    float m = fmaxf(m1a, m1b);
    float m2f = fmaxf(fmaxf(m2a, m2b), fminf(m1a, m1b));
    int idx = up ? i1 : i0;
    bool flg = (m - m2f) < DX;  // exact: final top-2 gap below margin
    float s = s0 + s1, u = u0 + u1;

    float ent = logf(s) - u / s;  // = lse - E[logit]
    float tau = 0.5f - 0.2f * (ent * (1.0f / (7.6246190071f + 1e-8f)));
    float simmax = fmaf(m, TEMPR, 1.0f);  // m is (sim-1)/T
    float dist = sqrtf(fmaxf(2.0f - 2.0f * simmax, 0.0f));
    int grow = row0 + wr * 32 + rowl;
    float g = CONF[idx] / (1.0f + __expf(-(BS[grow] - tau) * INV_T));
    gate_out[grow] = g;
    gd[grow] = g * dist;
    tau_ws[grow] = tau;
    if (flg) {
      int p = atomicAdd(cnt, 1);
      flags[p] = grow;
    }
  }
}

// ---------------- kernel 4: fp32 rescore of near-tie rows ----------------
__global__ __launch_bounds__(256) void krescore(
    const float* __restrict__ E, const float* __restrict__ P,
    const float* __restrict__ BS, const float* __restrict__ CONF,
    const float* __restrict__ tau_ws, const int* __restrict__ cnt,
    const int* __restrict__ flags, float* __restrict__ gd,
    float* __restrict__ gate_out) {
  __shared__ float en[512];
  __shared__ float red[256];
  __shared__ int redi[256];
  __shared__ float sinv;
  const int n = *cnt;
  const int t = threadIdx.x;
  for (int j = blockIdx.x; j < n; j += gridDim.x) {
    const int row = flags[j];
    float2 v = ((const float2*)(E + (size_t)row * ND))[t];
    red[t] = v.x * v.x + v.y * v.y;
    __syncthreads();
    for (int o = 128; o > 0; o >>= 1) {
      if (t < o) red[t] += red[t + o];
      __syncthreads();
    }
    if (t == 0) sinv = 1.0f / fmaxf(sqrtf(red[0]), 1e-12f);
    __syncthreads();
    en[2 * t] = v.x * sinv;
    en[2 * t + 1] = v.y * sinv;
    __syncthreads();
    float best = -3.0e38f;
    int bidx = 0;
    for (int k = 0; k < 8; ++k) {
      const int p = k * 256 + t;
      const float4* pr = (const float4*)(P + (size_t)p * ND);
      float dot = 0.f, pp = 0.f;
      for (int i = 0; i < 128; ++i) {
        float4 a = pr[i];
        float4 e4 = ((const float4*)en)[i];
        dot = fmaf(a.x, e4.x, dot); dot = fmaf(a.y, e4.y, dot);
        dot = fmaf(a.z, e4.z, dot); dot = fmaf(a.w, e4.w, dot);
        pp = fmaf(a.x, a.x, pp); pp = fmaf(a.y, a.y, pp);
        pp = fmaf(a.z, a.z, pp); pp = fmaf(a.w, a.w, pp);
      }
      float sim = dot / fmaxf(sqrtf(pp), 1e-12f);
      if (sim > best) { best = sim; bidx = p; }  // ascending p: first-max kept
    }
    red[t] = best;
    redi[t] = bidx;
    __syncthreads();
    if (t == 0) {
      float bb = red[0];
      int bi = redi[0];
      for (int i = 1; i < 256; ++i) {
        float vv = red[i];
        int ii = redi[i];
        if (vv > bb || (vv == bb && ii < bi)) { bb = vv; bi = ii; }
      }
      float tau = tau_ws[row];
      float dist = sqrtf(fmaxf(2.0f - 2.0f * bb, 0.0f));
      float g = CONF[bi] / (1.0f + __expf(-(BS[row] - tau) * INV_T));
      gate_out[row] = g;
      gd[row] = g * dist;
    }
    __syncthreads();
  }
}

// ---------------- kernel 5: deterministic mean ----------------
__global__ __launch_bounds__(1024) void kreduce(const float* __restrict__ gd,
                                                float* __restrict__ out0) {
  __shared__ float red[1024];
  const int t = threadIdx.x;
  float s = 0.f;
  const float4* g4 = (const float4*)gd;
  for (int i = t; i < 8192; i += 1024) {
    float4 v = g4[i];
    s += (v.x + v.y) + (v.z + v.w);
  }
  red[t] = s;
  __syncthreads();
  for (int off = 512; off > 0; off >>= 1) {
    if (t < off) red[t] += red[t + off];
    __syncthreads();
  }
  if (t == 0) out0[0] = red[0] * (1.0f / 32768.0f);
}

extern "C" void kernel_launch(void* const* d_in, const int* in_sizes, int n_in,
                              void* d_out, int out_size, void* d_ws, size_t ws_size,
                              hipStream_t stream) {
  const float* E = (const float*)d_in[0];
  const float* BS = (const float*)d_in[1];
  const float* P = (const float*)d_in[2];
  const float* CONF = (const float*)d_in[3];
  float* out = (float*)d_out;  // [0]=L_proto, [1..32768]=gate

  char* wsb = (char*)d_ws;
  u16* Phi = (u16*)wsb;                                   // 2 MB @ 0
  u16* Plo = (u16*)(wsb + ((size_t)2 << 20));             // 2 MB @ 2M
  u16* Ehi = (u16*)(wsb + ((size_t)4 << 20));             // 32 MB @ 4M
  u16* Elo = (u16*)(wsb + ((size_t)36 << 20));            // 32 MB @ 36M
  float* tau_ws = (float*)(wsb + ((size_t)68 << 20));     // 128 KB
  float* gd = (float*)(wsb + ((size_t)68 << 20) + 131072);
  int* flags = (int*)(wsb + ((size_t)68 << 20) + 2 * 131072);
  int* cnt = (int*)(wsb + ((size_t)68 << 20) + 3 * 131072);

  kprep_p<<<512, 256, 0, stream>>>(P, Phi, Plo, cnt);
  kprep_e2<<<8192, 256, 0, stream>>>(E, Ehi, Elo);
  kmain_v5<<<512, 256, 0, stream>>>(BS, Phi, Plo, Ehi, Elo, CONF, tau_ws, gd,
                                    out + 1, cnt, flags);
  krescore<<<64, 256, 0, stream>>>(E, P, BS, CONF, tau_ws, cnt, flags, gd, out + 1);
  kreduce<<<1, 1024, 0, stream>>>(gd, out);
}